// Round 8
// baseline (110.644 us; speedup 1.0000x reference)
//
#include <hip/hip_runtime.h>
#include <hip/hip_bf16.h>

// MoE conv via bf16 MFMA implicit GEMM, tap-decomposed, BARRIER-FREE K-loop.
// x: [32,64,64,64] f32  idx: [32] i32  Wc: [4,128,64,3,3] f32 (294,912 floats
// total, 73,728/expert)  bc: [4,128] f32  out: [32,128,64,64] f32
//
// Pre-kernel: linear transpose Wc -> d_ws bf16 [e][tap][ich(8)][oc(128)][icl(8)].
// Main: 512 threads = 8 waves: 1 sample x 128 oc x (4 rows x 64 cols).
// Wave = 64oc x 64px: 2x2 accs of mfma_f32_32x32x16_bf16.
// A-fragments are 16B-contiguous in wre -> loaded DIRECTLY from global (L2-hot,
// 576 KB working set), so there is no weight LDS, no per-tap staging, and the
// K-loop has ZERO barriers (xs written once, read-only after one barrier).
// LDS 50.7 KB; grid 512 = 2 blocks/CU exact residency, 16 waves/CU hide L2 lat.

#define IC 64
#define OC 128
#define HH 64
#define WW 64

typedef short short8 __attribute__((ext_vector_type(8)));
typedef float float16 __attribute__((ext_vector_type(16)));

static __device__ __forceinline__ ushort f2bf(float v) {
    __hip_bfloat16 h = __float2bfloat16(v);
    return *(ushort*)&h;
}

// ---------------- pre-kernel: reorder + convert weights (R6-proven) ----------------
__global__ __launch_bounds__(256)
void reorder_w(const float* __restrict__ Wc, ushort* __restrict__ wout) {
    const int n = blockIdx.x * 256 + threadIdx.x;   // 0 .. 294,911
    const float v = Wc[n];
    const int e  = n / 73728;                       // 128*64*9
    int r        = n - e * 73728;
    const int oc = r / 576;                         // 64*9
    r           -= oc * 576;
    const int ic  = r / 9;
    const int tap = r - ic * 9;
    wout[((((size_t)e * 9 + tap) * 8 + (ic >> 3)) * 128 + oc) * 8 + (ic & 7)] =
        f2bf(v);
}

// ---------------- main kernel ----------------
__global__ __launch_bounds__(512)
void moe_conv_mfma(const float* __restrict__ x, const int* __restrict__ idx,
                   const ushort* __restrict__ wre, const float* __restrict__ bc,
                   float* __restrict__ out) {
    __shared__ __align__(16) ushort xs[6 * 8 * 66 * 8];  // [r][ich][hc][icl] 50688 B

    const int t    = threadIdx.x;
    const int rq   = blockIdx.x;          // row quad 0..15
    const int b    = blockIdx.y;          // sample
    const int row0 = rq * 4;
    const int e    = ((unsigned)idx[b]) & 3;   // hardened expert index

    // --- halo-column zeros (hc = 0, 65) ---
    if (t < 192) {  // r(6) x ich(8) x side(2) x q(2)
        const int r = t >> 5, rem = t & 31;
        const int ich = rem >> 2, side = (rem >> 1) & 1, q = rem & 1;
        const int hc = side ? 65 : 0;
        ushort4 z = {0, 0, 0, 0};
        *(ushort4*)&xs[(((r * 8 + ich) * 66 + hc) * 8 + q * 4)] = z;
    }

    // --- x staging: fp32 [ic][h][w] -> bf16 [r(6)][ich][hc][icl] ---
    const float* xb = x + (size_t)b * IC * HH * WW;
    {
        const int gc   = t & 63;          // coalesced lane = w
        const int csel = t >> 6;          // 0..7
#pragma unroll
        for (int it = 0; it < 12; ++it) {
            const int combo = it * 8 + csel;       // 0..95 = r(6) x ich(8) x q(2)
            const int r = combo >> 4, rem = combo & 15;
            const int ich = rem >> 1, q = rem & 1;
            const int gr = row0 - 1 + r;
            ushort4 u = {0, 0, 0, 0};
            if ((unsigned)gr < (unsigned)HH) {
                const int ic0 = ich * 8 + q * 4;
                u.x = f2bf(xb[((ic0 + 0) * HH + gr) * WW + gc]);
                u.y = f2bf(xb[((ic0 + 1) * HH + gr) * WW + gc]);
                u.z = f2bf(xb[((ic0 + 2) * HH + gr) * WW + gc]);
                u.w = f2bf(xb[((ic0 + 3) * HH + gr) * WW + gc]);
            }
            *(ushort4*)&xs[(((r * 8 + ich) * 66 + (gc + 1)) * 8 + q * 4)] = u;
        }
    }

    // --- per-lane MFMA coordinates ---
    const int lane31 = t & 31;
    const int lhi    = (t >> 5) & 1;
    const int wv     = t >> 6;            // 0..7
    const int w0     = wv & 1;            // oc half
    const int pr     = wv >> 1;           // output row within quad, 0..3

    // --- acc init = bias (wave-uniform L2-hot scalar loads) ---
    float16 acc[2][2];
#pragma unroll
    for (int a = 0; a < 2; ++a) {
        const int ocb = w0 * 64 + a * 32 + 4 * lhi;
#pragma unroll
        for (int reg = 0; reg < 16; ++reg) {
            const float bv = bc[e * OC + ocb + (reg & 3) + 8 * (reg >> 2)];
            acc[a][0][reg] = bv;
            acc[a][1][reg] = bv;
        }
    }

    __syncthreads();   // xs (halo + staged rows) ready — the ONLY barrier

    const ushort* wexp = wre + (size_t)e * 73728;   // 9*8192 per expert

    for (int tap = 0; tap < 9; ++tap) {
        const int kh = tap / 3;
        const int kw = tap - kh * 3;
        const int rr = pr + kh;              // staged row 0..5
        const int hb = lane31 + kw;          // halo col for cg=0
        const ushort* wtap = wexp + tap * 8192;

#pragma unroll
        for (int ks = 0; ks < 4; ++ks) {
            const int ich = ks * 2 + lhi;
            // A-frags direct from global (16 B contiguous, L2-resident):
            const short8 a0 = *(const short8*)(wtap + (ich * 128 + w0 * 64 + lane31) * 8);
            const short8 a1 = *(const short8*)(wtap + (ich * 128 + w0 * 64 + 32 + lane31) * 8);
            const short8 b0 = *(const short8*)&xs[((rr * 8 + ich) * 66 + hb) * 8];
            const short8 b1 = *(const short8*)&xs[((rr * 8 + ich) * 66 + hb + 32) * 8];
            acc[0][0] = __builtin_amdgcn_mfma_f32_32x32x16_bf16(a0, b0, acc[0][0], 0, 0, 0);
            acc[0][1] = __builtin_amdgcn_mfma_f32_32x32x16_bf16(a0, b1, acc[0][1], 0, 0, 0);
            acc[1][0] = __builtin_amdgcn_mfma_f32_32x32x16_bf16(a1, b0, acc[1][0], 0, 0, 0);
            acc[1][1] = __builtin_amdgcn_mfma_f32_32x32x16_bf16(a1, b1, acc[1][1], 0, 0, 0);
        }
    }

    // --- epilogue: C/D layout col=lane&31, row=(reg&3)+8*(reg>>2)+4*(lane>>5) ---
    // (bias already in acc)
#pragma unroll
    for (int a = 0; a < 2; ++a) {
        const int ocb = w0 * 64 + a * 32 + 4 * lhi;
#pragma unroll
        for (int reg = 0; reg < 16; ++reg) {
            const int oc = ocb + (reg & 3) + 8 * (reg >> 2);
            const size_t base = (((size_t)b * OC + oc) * HH + (row0 + pr)) * WW;
            out[base + lane31]      = acc[a][0][reg];
            out[base + 32 + lane31] = acc[a][1][reg];
        }
    }
}

extern "C" void kernel_launch(void* const* d_in, const int* in_sizes, int n_in,
                              void* d_out, int out_size, void* d_ws, size_t ws_size,
                              hipStream_t stream) {
    const float* x   = (const float*)d_in[0];
    const int*   idx = (const int*)d_in[1];
    const float* Wc  = (const float*)d_in[2];
    const float* bc  = (const float*)d_in[3];
    float* out  = (float*)d_out;
    ushort* wre = (ushort*)d_ws;   // 294,912 bf16 = 576 KB scratch

    reorder_w<<<1152, 256, 0, stream>>>(Wc, wre);   // 1152*256 = 294,912 = |Wc|
    dim3 grid(16, 32);             // row-quads x samples = 512 blocks
    moe_conv_mfma<<<grid, 512, 0, stream>>>(x, idx, wre, bc, out);
}

// Round 9
// 110.489 us; speedup vs baseline: 1.0014x; 1.0014x over previous
//
#include <hip/hip_runtime.h>
#include <hip/hip_bf16.h>

// MoE conv via bf16 MFMA implicit GEMM, tap-decomposed, barrier-free K-loop.
// x: [32,64,64,64] f32  idx: [32] i32  Wc: [4,128,64,3,3] f32 (294,912 floats
// total, 73,728/expert)  bc: [4,128] f32  out: [32,128,64,64] f32
//
// Pre-kernel: linear transpose Wc -> d_ws bf16 [e][tap][ich(8)][oc(128)][icl(8)].
// Main: 512 threads = 8 waves: 1 sample x 128 oc x (4 rows x 64 cols).
// Wave = 64oc x 64px: 2x2 accs of mfma_f32_32x32x16_bf16. A-frags direct from
// L2-resident wre (16B contiguous); zero K-loop barriers.
// __launch_bounds__(512,4): force <=128 VGPR so 2 blocks/CU actually fit
// (grid 512 = exact full residency, 16 waves/CU to hide L2 latency).

#define IC 64
#define OC 128
#define HH 64
#define WW 64

typedef short short8 __attribute__((ext_vector_type(8)));
typedef float float16 __attribute__((ext_vector_type(16)));

static __device__ __forceinline__ ushort f2bf(float v) {
    __hip_bfloat16 h = __float2bfloat16(v);
    return *(ushort*)&h;
}

// ---------------- pre-kernel: reorder + convert weights (R6-proven) ----------------
__global__ __launch_bounds__(256)
void reorder_w(const float* __restrict__ Wc, ushort* __restrict__ wout) {
    const int n = blockIdx.x * 256 + threadIdx.x;   // 0 .. 294,911
    const float v = Wc[n];
    const int e  = n / 73728;                       // 128*64*9
    int r        = n - e * 73728;
    const int oc = r / 576;                         // 64*9
    r           -= oc * 576;
    const int ic  = r / 9;
    const int tap = r - ic * 9;
    wout[((((size_t)e * 9 + tap) * 8 + (ic >> 3)) * 128 + oc) * 8 + (ic & 7)] =
        f2bf(v);
}

// ---------------- main kernel ----------------
__global__ __launch_bounds__(512, 4)
void moe_conv_mfma(const float* __restrict__ x, const int* __restrict__ idx,
                   const ushort* __restrict__ wre, const float* __restrict__ bc,
                   float* __restrict__ out) {
    __shared__ __align__(16) ushort xs[6 * 8 * 66 * 8];  // [r][ich][hc][icl] 50688 B

    const int t    = threadIdx.x;
    const int rq   = blockIdx.x;          // row quad 0..15
    const int b    = blockIdx.y;          // sample
    const int row0 = rq * 4;
    const int e    = ((unsigned)idx[b]) & 3;   // hardened expert index

    // --- halo-column zeros (hc = 0, 65) ---
    if (t < 192) {  // r(6) x ich(8) x side(2) x q(2)
        const int r = t >> 5, rem = t & 31;
        const int ich = rem >> 2, side = (rem >> 1) & 1, q = rem & 1;
        const int hc = side ? 65 : 0;
        ushort4 z = {0, 0, 0, 0};
        *(ushort4*)&xs[(((r * 8 + ich) * 66 + hc) * 8 + q * 4)] = z;
    }

    // --- x staging: fp32 [ic][h][w] -> bf16 [r(6)][ich][hc][icl] ---
    const float* xb = x + (size_t)b * IC * HH * WW;
    {
        const int gc   = t & 63;          // coalesced lane = w
        const int csel = t >> 6;          // 0..7
#pragma unroll
        for (int it = 0; it < 12; ++it) {
            const int combo = it * 8 + csel;       // 0..95 = r(6) x ich(8) x q(2)
            const int r = combo >> 4, rem = combo & 15;
            const int ich = rem >> 1, q = rem & 1;
            const int gr = row0 - 1 + r;
            ushort4 u = {0, 0, 0, 0};
            if ((unsigned)gr < (unsigned)HH) {
                const int ic0 = ich * 8 + q * 4;
                u.x = f2bf(xb[((ic0 + 0) * HH + gr) * WW + gc]);
                u.y = f2bf(xb[((ic0 + 1) * HH + gr) * WW + gc]);
                u.z = f2bf(xb[((ic0 + 2) * HH + gr) * WW + gc]);
                u.w = f2bf(xb[((ic0 + 3) * HH + gr) * WW + gc]);
            }
            *(ushort4*)&xs[(((r * 8 + ich) * 66 + (gc + 1)) * 8 + q * 4)] = u;
        }
    }

    // --- per-lane MFMA coordinates ---
    const int lane31 = t & 31;
    const int lhi    = (t >> 5) & 1;
    const int wv     = t >> 6;            // 0..7
    const int w0     = wv & 1;            // oc half
    const int pr     = wv >> 1;           // output row within quad, 0..3

    // --- acc init = bias (wave-uniform L2-hot scalar loads) ---
    float16 acc[2][2];
#pragma unroll
    for (int a = 0; a < 2; ++a) {
        const int ocb = w0 * 64 + a * 32 + 4 * lhi;
#pragma unroll
        for (int reg = 0; reg < 16; ++reg) {
            const float bv = bc[e * OC + ocb + (reg & 3) + 8 * (reg >> 2)];
            acc[a][0][reg] = bv;
            acc[a][1][reg] = bv;
        }
    }

    __syncthreads();   // xs ready — the ONLY barrier

    const ushort* wexp = wre + (size_t)e * 73728;   // 9*8192 per expert
    const ushort* wtap = wexp;

    for (int kh = 0; kh < 3; ++kh) {
        const int rr = pr + kh;              // staged row 0..5
#pragma unroll
        for (int kw = 0; kw < 3; ++kw) {
            const int hb = lane31 + kw;      // halo col for cg=0
#pragma unroll
            for (int ks = 0; ks < 4; ++ks) {
                const int ich = ks * 2 + lhi;
                const short8 a0 = *(const short8*)(wtap + (ich * 128 + w0 * 64 + lane31) * 8);
                const short8 a1 = *(const short8*)(wtap + (ich * 128 + w0 * 64 + 32 + lane31) * 8);
                const short8 b0 = *(const short8*)&xs[((rr * 8 + ich) * 66 + hb) * 8];
                const short8 b1 = *(const short8*)&xs[((rr * 8 + ich) * 66 + hb + 32) * 8];
                acc[0][0] = __builtin_amdgcn_mfma_f32_32x32x16_bf16(a0, b0, acc[0][0], 0, 0, 0);
                acc[0][1] = __builtin_amdgcn_mfma_f32_32x32x16_bf16(a0, b1, acc[0][1], 0, 0, 0);
                acc[1][0] = __builtin_amdgcn_mfma_f32_32x32x16_bf16(a1, b0, acc[1][0], 0, 0, 0);
                acc[1][1] = __builtin_amdgcn_mfma_f32_32x32x16_bf16(a1, b1, acc[1][1], 0, 0, 0);
            }
            wtap += 8192;
        }
    }

    // --- epilogue: C/D layout col=lane&31, row=(reg&3)+8*(reg>>2)+4*(lane>>5) ---
#pragma unroll
    for (int a = 0; a < 2; ++a) {
        const int ocb = w0 * 64 + a * 32 + 4 * lhi;
#pragma unroll
        for (int reg = 0; reg < 16; ++reg) {
            const int oc = ocb + (reg & 3) + 8 * (reg >> 2);
            const size_t base = (((size_t)b * OC + oc) * HH + (row0 + pr)) * WW;
            out[base + lane31]      = acc[a][0][reg];
            out[base + 32 + lane31] = acc[a][1][reg];
        }
    }
}

extern "C" void kernel_launch(void* const* d_in, const int* in_sizes, int n_in,
                              void* d_out, int out_size, void* d_ws, size_t ws_size,
                              hipStream_t stream) {
    const float* x   = (const float*)d_in[0];
    const int*   idx = (const int*)d_in[1];
    const float* Wc  = (const float*)d_in[2];
    const float* bc  = (const float*)d_in[3];
    float* out  = (float*)d_out;
    ushort* wre = (ushort*)d_ws;   // 294,912 bf16 = 576 KB scratch

    reorder_w<<<1152, 256, 0, stream>>>(Wc, wre);   // 1152*256 = 294,912 = |Wc|
    dim3 grid(16, 32);             // row-quads x samples = 512 blocks
    moe_conv_mfma<<<grid, 512, 0, stream>>>(x, idx, wre, bc, out);
}